// Round 4
// baseline (1274.781 us; speedup 1.0000x reference)
//
#include <hip/hip_runtime.h>
#include <math.h>
#include <stdint.h>

#define B_    32
#define H_    32
#define KVH_  8
#define D_    128
#define HID_  4096
#define SEQ_  2048
#define QKVF_ 6144
#define SCALE_ 0.08838834764831845f   // 1/sqrt(128)
#define NCHUNK 8
#define CHUNK_ 256
#define TROWS  32
#define NTILE  8

typedef const __attribute__((address_space(1))) uint32_t* gp_t;
typedef __attribute__((address_space(3))) uint32_t* lp_t;

__device__ __forceinline__ void dma16(const float* src, float* ldsdst) {
    __builtin_amdgcn_global_load_lds((gp_t)src, (lp_t)ldsdst, 16, 0, 0);
}

// ---------------- GEMV: qkv[b][f] = dot(w_f, x_b) ----------------
// lane = (f-octet | b-octet): 8 distinct w-rows x 16B = 128B unique/instr.
__global__ __launch_bounds__(256) void gemm_qkv(const float* __restrict__ wq,
                                                const float* __restrict__ wk,
                                                const float* __restrict__ wv,
                                                const float* __restrict__ x,
                                                float* __restrict__ qkv) {
    int w = threadIdx.x >> 6, lane = threadIdx.x & 63;
    int f = blockIdx.x * 8 + (lane & 7);
    int bb = w * 8 + (lane >> 3);
    const float* wrow;                     // uniform per block (f spans 8)
    if (f < HID_)             wrow = wq + (size_t)f * HID_;
    else if (f < HID_ + 1024) wrow = wk + (size_t)(f - HID_) * HID_;
    else                      wrow = wv + (size_t)(f - HID_ - 1024) * HID_;
    const float4* wp = (const float4*)wrow;
    const float4* xp = (const float4*)(x + (size_t)bb * HID_);
    float ax = 0.f, ay = 0.f, az = 0.f, aw = 0.f;
#pragma unroll 8
    for (int k = 0; k < 1024; ++k) {
        float4 wv4 = wp[k];
        float4 xv4 = xp[k];
        ax = fmaf(wv4.x, xv4.x, ax);
        ay = fmaf(wv4.y, xv4.y, ay);
        az = fmaf(wv4.z, xv4.z, az);
        aw = fmaf(wv4.w, xv4.w, aw);
    }
    qkv[bb * QKVF_ + f] = (ax + ay) + (az + aw);
}

// ---------------- RMSNorm + RoPE (q pre-scaled by 1/sqrt(D)) ----------------
__global__ __launch_bounds__(256) void norm_rope(const float* __restrict__ qkv,
                                                 const float* __restrict__ qnw,
                                                 const float* __restrict__ knw,
                                                 const float* __restrict__ cosT,
                                                 const float* __restrict__ sinT,
                                                 const int* __restrict__ pos_ids,
                                                 float* __restrict__ qhat,
                                                 float* __restrict__ khat) {
    int u = blockIdx.x * 4 + (threadIdx.x >> 6);   // 0..1279 = 32 b * 40 heads
    int l = threadIdx.x & 63;
    int b  = u / 40;
    int hh = u % 40;
    bool isq = hh < 32;
    const float* src = qkv + b * QKVF_ + (isq ? hh * D_ : HID_ + (hh - 32) * D_);
    float v0 = src[l];
    float v1 = src[l + 64];
    float ss = v0 * v0 + v1 * v1;
#pragma unroll
    for (int m = 1; m <= 32; m <<= 1) ss += __shfl_xor(ss, m, 64);
    float r = rsqrtf(ss * (1.0f / 128.0f) + 1e-6f);
    const float* nw = isq ? qnw : knw;
    float n0 = v0 * r * nw[l];
    float n1 = v1 * r * nw[l + 64];
    int pos = pos_ids[b];
    const float* cp = cosT + (size_t)pos * D_;
    const float* sp = sinT + (size_t)pos * D_;
    float o0 = n0 * cp[l]      - n1 * sp[l];
    float o1 = n1 * cp[l + 64] + n0 * sp[l + 64];
    if (isq) { o0 *= SCALE_; o1 *= SCALE_; }
    float* dst = isq ? (qhat + (size_t)(b * 32 + hh) * D_)
                     : (khat + (size_t)(b * 8 + (hh - 32)) * D_);
    dst[l]      = o0;
    dst[l + 64] = o1;
}

// ---------------- flash-decode attention ----------------
// block = (b, kvh, chunk of 256 rows); 4 waves. Per 32-row tile:
//   waves 0..3 each score 8 rows for all 4 heads; wave w does PV for head w.
// K staged swizzled (source-permuted, LDS-linear); V staged linear.
__global__ __launch_bounds__(256) void attn_fd(const float* __restrict__ qhat,
                                               const float* __restrict__ khat,
                                               const float* __restrict__ qkv,
                                               const float* __restrict__ kcache,
                                               const float* __restrict__ vcache,
                                               float* __restrict__ part) {
    __shared__ float Kl[TROWS * 128];   // swizzled within-row (f4 slots)
    __shared__ float Vl[TROWS * 128];   // linear
    __shared__ float Ql[4 * 128];       // rotated q slots
    __shared__ float Pb[4 * TROWS];     // p_tile [head][row]
    __shared__ float Ms[16];            // [scorewave][head] tile max
    __shared__ float Ls[16];            // [scorewave][head] tile sum

    int tid = threadIdx.x;
    int w = tid >> 6, lane = tid & 63;
    int bi = blockIdx.x;
    int chunk = bi & 7, kvh = (bi >> 3) & 7, b = bi >> 6;

    const float* kbase = kcache + ((size_t)b * SEQ_ * KVH_ + kvh) * D_;
    const float* vbase = vcache + ((size_t)b * SEQ_ * KVH_ + kvh) * D_;
    const float* knew  = khat + (size_t)(b * KVH_ + kvh) * D_;
    const float* vnew  = qkv + b * QKVF_ + HID_ + KVH_ * D_ + kvh * D_;
    int row0 = chunk * CHUNK_;

    // stage q (threads 0..127), rotated within each d8 quarter-of-4
    if (tid < 128) {
        int h = tid >> 5, tl = tid & 31;
        float4 qv = ((const float4*)(qhat + (size_t)((b * H_ + kvh * 4 + h) * D_)))[tl];
        int phys = (tl & 28) | ((tl + (tl >> 2)) & 3);
        *(float4*)(Ql + h * 128 + phys * 4) = qv;
    }

    // issue K tile-0 DMA (4 loads/thread)
#pragma unroll
    for (int p = 0; p < 4; ++p) {
        int i = tid + p * 256;
        int r = i >> 5, c = i & 31;
        int l = (c & 24) | ((c ^ r) & 7);        // source-permuted (LDS linear)
        int grow = row0 + r;
        const float* src = (grow == SEQ_ - 1) ? (knew + l * 4)
                          : (kbase + (size_t)grow * (KVH_ * D_) + l * 4);
        dma16(src, Kl + i * 4);
    }

    float m_run = -3.4e38f, lsum = 0.f, O0 = 0.f, O1 = 0.f;
    int r8 = lane >> 3, d8 = lane & 7;
    int srow = w * 8 + r8;
    int kswz = srow & 7;

    for (int tile = 0; tile < NTILE; ++tile) {
        // a) issue V DMA (overlaps with score phase)
#pragma unroll
        for (int p = 0; p < 4; ++p) {
            int i = tid + p * 256;
            int r = i >> 5, c = i & 31;
            int grow = row0 + tile * TROWS + r;
            const float* src = (grow == SEQ_ - 1) ? (vnew + c * 4)
                              : (vbase + (size_t)grow * (KVH_ * D_) + c * 4);
            dma16(src, Vl + i * 4);
        }
        // b,c) counted wait: oldest 4 (K) landed; raw barrier (keep V in flight)
        asm volatile("s_waitcnt vmcnt(4) lgkmcnt(0)" ::: "memory");
        __builtin_amdgcn_s_barrier();

        // d) score: lane (r8, d8) computes d-eighth dots for 4 heads
        float s0 = 0.f, s1 = 0.f, s2 = 0.f, s3 = 0.f;
#pragma unroll
        for (int t = 0; t < 4; ++t) {
            int l = d8 * 4 + t;
            int phys = (l & 24) | ((l ^ kswz) & 7);
            float4 k4 = *(const float4*)(Kl + srow * 128 + phys * 4);
            int qp = d8 * 4 + ((t + d8) & 3);
            float4 qa = *(const float4*)(Ql + 0 * 128 + qp * 4);
            float4 qb = *(const float4*)(Ql + 1 * 128 + qp * 4);
            float4 qc = *(const float4*)(Ql + 2 * 128 + qp * 4);
            float4 qd = *(const float4*)(Ql + 3 * 128 + qp * 4);
            s0 = fmaf(qa.x, k4.x, fmaf(qa.y, k4.y, fmaf(qa.z, k4.z, fmaf(qa.w, k4.w, s0))));
            s1 = fmaf(qb.x, k4.x, fmaf(qb.y, k4.y, fmaf(qb.z, k4.z, fmaf(qb.w, k4.w, s1))));
            s2 = fmaf(qc.x, k4.x, fmaf(qc.y, k4.y, fmaf(qc.z, k4.z, fmaf(qc.w, k4.w, s2))));
            s3 = fmaf(qd.x, k4.x, fmaf(qd.y, k4.y, fmaf(qd.z, k4.z, fmaf(qd.w, k4.w, s3))));
        }
#pragma unroll
        for (int m = 1; m <= 4; m <<= 1) {       // reduce over d8
            s0 += __shfl_xor(s0, m, 64);
            s1 += __shfl_xor(s1, m, 64);
            s2 += __shfl_xor(s2, m, 64);
            s3 += __shfl_xor(s3, m, 64);
        }
        int hsel = d8 & 3;
        float s = (hsel == 0) ? s0 : (hsel == 1) ? s1 : (hsel == 2) ? s2 : s3;
        // per-(wave,head) tile max over the wave's 8 rows
        float mx = s;
        mx = fmaxf(mx, __shfl_xor(mx, 8, 64));
        mx = fmaxf(mx, __shfl_xor(mx, 16, 64));
        mx = fmaxf(mx, __shfl_xor(mx, 32, 64));
        float pt = __expf(s - mx);               // one exp per (row,head)
        if (d8 < 4) Pb[hsel * TROWS + srow] = pt;
        float ps = pt;
        ps += __shfl_xor(ps, 8, 64);
        ps += __shfl_xor(ps, 16, 64);
        ps += __shfl_xor(ps, 32, 64);
        if (r8 == 0 && d8 < 4) { Ms[w * 4 + d8] = mx; Ls[w * 4 + d8] = ps; }

        // f,g) drain V + ds-writes, full barrier
        __syncthreads();

        // h) issue next K DMA (stays in flight through PV and barrier j)
        if (tile + 1 < NTILE) {
#pragma unroll
            for (int p = 0; p < 4; ++p) {
                int i = tid + p * 256;
                int r = i >> 5, c = i & 31;
                int l = (c & 24) | ((c ^ r) & 7);
                int grow = row0 + (tile + 1) * TROWS + r;
                const float* src = (grow == SEQ_ - 1) ? (knew + l * 4)
                                  : (kbase + (size_t)grow * (KVH_ * D_) + l * 4);
                dma16(src, Kl + i * 4);
            }
        }

        // i) PV: wave w = head w
        float mw0 = Ms[0 * 4 + w], mw1 = Ms[1 * 4 + w], mw2 = Ms[2 * 4 + w], mw3 = Ms[3 * 4 + w];
        float mt = fmaxf(fmaxf(mw0, mw1), fmaxf(mw2, mw3));
        float m_new = fmaxf(m_run, mt);
        float alpha = __expf(m_run - m_new);
        O0 *= alpha; lsum *= alpha; O1 *= alpha;
        m_run = m_new;
        float bw0 = __expf(mw0 - m_new), bw1 = __expf(mw1 - m_new);
        float bw2 = __expf(mw2 - m_new), bw3 = __expf(mw3 - m_new);
        lsum = fmaf(Ls[0 * 4 + w], bw0, lsum);
        lsum = fmaf(Ls[1 * 4 + w], bw1, lsum);
        lsum = fmaf(Ls[2 * 4 + w], bw2, lsum);
        lsum = fmaf(Ls[3 * 4 + w], bw3, lsum);
#pragma unroll
        for (int g2 = 0; g2 < 8; ++g2) {
            float bw = (g2 < 2) ? bw0 : (g2 < 4) ? bw1 : (g2 < 6) ? bw2 : bw3;
            float4 s4 = *(const float4*)(Pb + w * TROWS + g2 * 4);
#pragma unroll
            for (int j = 0; j < 4; ++j) {
                float pv = ((j == 0) ? s4.x : (j == 1) ? s4.y : (j == 2) ? s4.z : s4.w) * bw;
                float2 v2 = *(const float2*)(Vl + (g2 * 4 + j) * 128 + lane * 2);
                O0 = fmaf(pv, v2.x, O0);
                O1 = fmaf(pv, v2.y, O1);
            }
        }
        // j) full barrier (drains in-flight K too; it has had PV to land)
        __syncthreads();
    }

    size_t base = ((size_t)((b * KVH_ + kvh) * 4 + w) * NCHUNK + chunk) * 130;
    *(float2*)(part + base + 2 * lane) = make_float2(O0, O1);
    if (lane == 0) { part[base + 128] = m_run; part[base + 129] = lsum; }
}

// ---------------- combine chunk partials ----------------
__global__ __launch_bounds__(64) void combine(const float* __restrict__ part,
                                              float* __restrict__ aout) {
    int bi = blockIdx.x;                 // 1024 = 32 b * 32 heads
    int b = bi >> 5, hg = bi & 31;
    int kvh = hg >> 2, hl = hg & 3;
    int lane = threadIdx.x;
    size_t base0 = (size_t)((b * KVH_ + kvh) * 4 + hl) * NCHUNK * 130;
    float mstar = -3.4e38f;
#pragma unroll
    for (int c = 0; c < NCHUNK; ++c) mstar = fmaxf(mstar, part[base0 + c * 130 + 128]);
    float L = 0.f, A0 = 0.f, A1 = 0.f;
#pragma unroll
    for (int c = 0; c < NCHUNK; ++c) {
        float mc = part[base0 + c * 130 + 128];
        float lc = part[base0 + c * 130 + 129];
        float e = __expf(mc - mstar);
        L = fmaf(lc, e, L);
        float2 oc = *(const float2*)(part + base0 + c * 130 + 2 * lane);
        A0 = fmaf(oc.x, e, A0);
        A1 = fmaf(oc.y, e, A1);
    }
    float inv = 1.0f / L;
    size_t o = (size_t)b * HID_ + hg * D_ + 2 * lane;
    aout[o]     = A0 * inv;
    aout[o + 1] = A1 * inv;
}

// ---------------- GEMV: out[b][f] = dot(wo_f, aout_b) ----------------
__global__ __launch_bounds__(256) void gemm_o(const float* __restrict__ wo,
                                              const float* __restrict__ aout,
                                              float* __restrict__ out) {
    int w = threadIdx.x >> 6, lane = threadIdx.x & 63;
    int f = blockIdx.x * 8 + (lane & 7);
    int bb = w * 8 + (lane >> 3);
    const float4* wp = (const float4*)(wo + (size_t)f * HID_);
    const float4* xp = (const float4*)(aout + (size_t)bb * HID_);
    float ax = 0.f, ay = 0.f, az = 0.f, aw = 0.f;
#pragma unroll 8
    for (int k = 0; k < 1024; ++k) {
        float4 wv4 = wp[k];
        float4 xv4 = xp[k];
        ax = fmaf(wv4.x, xv4.x, ax);
        ay = fmaf(wv4.y, xv4.y, ay);
        az = fmaf(wv4.z, xv4.z, az);
        aw = fmaf(wv4.w, xv4.w, aw);
    }
    out[bb * HID_ + f] = (ax + ay) + (az + aw);
}

extern "C" void kernel_launch(void* const* d_in, const int* in_sizes, int n_in,
                              void* d_out, int out_size, void* d_ws, size_t ws_size,
                              hipStream_t stream) {
    const float* x      = (const float*)d_in[0];
    const float* wq     = (const float*)d_in[1];
    const float* wk     = (const float*)d_in[2];
    const float* wv     = (const float*)d_in[3];
    const float* wo     = (const float*)d_in[4];
    const float* qnw    = (const float*)d_in[5];
    const float* knw    = (const float*)d_in[6];
    const float* cosT   = (const float*)d_in[7];
    const float* sinT   = (const float*)d_in[8];
    const float* kcache = (const float*)d_in[9];
    const float* vcache = (const float*)d_in[10];
    const int*   pos    = (const int*)d_in[11];
    float* out = (float*)d_out;
    float* ws  = (float*)d_ws;

    float* qkv  = ws;                      // 196608
    float* qhat = ws + 196608;             // 131072
    float* khat = ws + 327680;             // 32768
    float* part = ws + 360448;             // 32*8*4*8*130 = 1064960
    float* aout = ws + 1425408;            // 131072  (total 1556480 floats)

    gemm_qkv<<<768, 256, 0, stream>>>(wq, wk, wv, x, qkv);
    norm_rope<<<320, 256, 0, stream>>>(qkv, qnw, knw, cosT, sinT, pos, qhat, khat);
    attn_fd<<<2048, 256, 0, stream>>>(qhat, khat, qkv, kcache, vcache, part);
    combine<<<1024, 64, 0, stream>>>(part, aout);
    gemm_o<<<512, 256, 0, stream>>>(wo, aout, out);
}